// Round 1
// baseline (112.485 us; speedup 1.0000x reference)
//
#include <hip/hip_runtime.h>
#include <math.h>

#define NN 8192
#define FF 128

// Kernel 1: per-row dual dot product. One wave (64 lanes) per row of x.
// lane l handles elements 2l, 2l+1 of the 128-wide row; butterfly-reduce.
__global__ __launch_bounds__(256) void compute_s_kernel(
    const float* __restrict__ x,   // (N, F)
    const float* __restrict__ W,   // (2F,)
    float* __restrict__ sL,        // (N,)
    float* __restrict__ sR)        // (N,)
{
    int gtid = blockIdx.x * blockDim.x + threadIdx.x;
    int row  = gtid >> 6;           // one 64-lane wave per row
    int lane = threadIdx.x & 63;
    if (row >= NN) return;

    const float2 xv = *reinterpret_cast<const float2*>(x + (size_t)row * FF + 2 * lane);
    const float2 wl = *reinterpret_cast<const float2*>(W + 2 * lane);
    const float2 wr = *reinterpret_cast<const float2*>(W + FF + 2 * lane);

    float accL = xv.x * wl.x + xv.y * wl.y;
    float accR = xv.x * wr.x + xv.y * wr.y;

    // 64-lane butterfly reduction (wave = 64 on CDNA4)
    #pragma unroll
    for (int off = 32; off > 0; off >>= 1) {
        accL += __shfl_xor(accL, off, 64);
        accR += __shfl_xor(accR, off, 64);
    }
    if (lane == 0) {
        sL[row] = accL;
        sR[row] = accR;
    }
}

// Kernel 2: out[i][j] = adj[i][j] * sigmoid(sL[i] + sR[j] + b)
// float4-vectorized grid-stride: each iteration handles 4 consecutive j.
__global__ __launch_bounds__(256) void dense_att_kernel(
    const float* __restrict__ adj,
    const float* __restrict__ sL,
    const float* __restrict__ sR,
    const float* __restrict__ bptr,
    float* __restrict__ out)
{
    const float b = *bptr;
    const long long total = (long long)NN * (NN / 4);   // float4 elements
    long long idx    = (long long)blockIdx.x * blockDim.x + threadIdx.x;
    long long stride = (long long)gridDim.x * blockDim.x;

    const float4* __restrict__ adj4 = reinterpret_cast<const float4*>(adj);
    const float4* __restrict__ sR4  = reinterpret_cast<const float4*>(sR);
    float4* __restrict__ out4       = reinterpret_cast<float4*>(out);

    for (; idx < total; idx += stride) {
        int i  = (int)(idx >> 11);       // NN/4 = 2048 float4 per row
        int jv = (int)(idx & 2047);

        float4 a = adj4[idx];
        float4 r = sR4[jv];
        float  s = sL[i] + b;

        float4 o;
        o.x = a.x * (1.0f / (1.0f + __expf(-(s + r.x))));
        o.y = a.y * (1.0f / (1.0f + __expf(-(s + r.y))));
        o.z = a.z * (1.0f / (1.0f + __expf(-(s + r.z))));
        o.w = a.w * (1.0f / (1.0f + __expf(-(s + r.w))));

        out4[idx] = o;
    }
}

extern "C" void kernel_launch(void* const* d_in, const int* in_sizes, int n_in,
                              void* d_out, int out_size, void* d_ws, size_t ws_size,
                              hipStream_t stream) {
    const float* x   = (const float*)d_in[0];   // (8192, 128)
    const float* adj = (const float*)d_in[1];   // (8192, 8192)
    const float* W   = (const float*)d_in[2];   // (256,)
    const float* b   = (const float*)d_in[3];   // scalar (1-elem device array)
    float* out = (float*)d_out;

    float* sL = (float*)d_ws;                   // 8192 floats
    float* sR = sL + NN;                        // 8192 floats

    // Kernel 1: 8192 waves = 2048 blocks of 256 threads (4 waves each)
    compute_s_kernel<<<NN / 4, 256, 0, stream>>>(x, W, sL, sR);

    // Kernel 2: memory-bound elementwise; 2048 blocks grid-stride
    dense_att_kernel<<<2048, 256, 0, stream>>>(adj, sL, sR, b, out);
}

// Round 3
// 97.207 us; speedup vs baseline: 1.1572x; 1.1572x over previous
//
#include <hip/hip_runtime.h>
#include <math.h>

#define NN 8192
#define FF 128

typedef float f32x4 __attribute__((ext_vector_type(4)));

// Kernel 1: per-row dual dot product. One wave (64 lanes) per row of x.
__global__ __launch_bounds__(256) void compute_s_kernel(
    const float* __restrict__ x,   // (N, F)
    const float* __restrict__ W,   // (2F,)
    float* __restrict__ sL,        // (N,)
    float* __restrict__ sR)        // (N,)
{
    int gtid = blockIdx.x * blockDim.x + threadIdx.x;
    int row  = gtid >> 6;           // one 64-lane wave per row
    int lane = threadIdx.x & 63;
    if (row >= NN) return;

    const float2 xv = *reinterpret_cast<const float2*>(x + (size_t)row * FF + 2 * lane);
    const float2 wl = *reinterpret_cast<const float2*>(W + 2 * lane);
    const float2 wr = *reinterpret_cast<const float2*>(W + FF + 2 * lane);

    float accL = xv.x * wl.x + xv.y * wl.y;
    float accR = xv.x * wr.x + xv.y * wr.y;

    #pragma unroll
    for (int off = 32; off > 0; off >>= 1) {
        accL += __shfl_xor(accL, off, 64);
        accR += __shfl_xor(accR, off, 64);
    }
    if (lane == 0) {
        sL[row] = accL;
        sR[row] = accR;
    }
}

__device__ __forceinline__ float fast_sigmoid(float z) {
    // sigmoid(z) = 1/(1+exp(-z)); v_rcp_f32 is ~1 ulp, far under the 2e-2 threshold
    return __builtin_amdgcn_rcpf(1.0f + __expf(-z));
}

// Kernel 2: one block per row. out[i][j] = adj[i][j] * sigmoid(sL[i] + sR[j] + b)
// Each thread: 8 float4 elements, loads issued 8-deep before compute.
__global__ __launch_bounds__(256) void dense_att_row_kernel(
    const float* __restrict__ adj,
    const float* __restrict__ sL,
    const float* __restrict__ sR,
    const float* __restrict__ bptr,
    float* __restrict__ out)
{
    const int row = blockIdx.x;
    const int tid = threadIdx.x;

    const f32x4* __restrict__ adjr = reinterpret_cast<const f32x4*>(adj) + (size_t)row * (NN / 4);
    const f32x4* __restrict__ sR4  = reinterpret_cast<const f32x4*>(sR);
    f32x4* __restrict__ outr       = reinterpret_cast<f32x4*>(out) + (size_t)row * (NN / 4);

    const float s = sL[row] + *bptr;

    f32x4 a[8], r[8];
    // Issue all 16 loads first — deep MLP, no dependent address math.
    #pragma unroll
    for (int k = 0; k < 8; ++k) {
        a[k] = __builtin_nontemporal_load(&adjr[tid + 256 * k]);   // stream, don't cache
    }
    #pragma unroll
    for (int k = 0; k < 8; ++k) {
        r[k] = sR4[tid + 256 * k];                                  // L1/L2-resident
    }

    #pragma unroll
    for (int k = 0; k < 8; ++k) {
        f32x4 o;
        o.x = a[k].x * fast_sigmoid(s + r[k].x);
        o.y = a[k].y * fast_sigmoid(s + r[k].y);
        o.z = a[k].z * fast_sigmoid(s + r[k].z);
        o.w = a[k].w * fast_sigmoid(s + r[k].w);
        __builtin_nontemporal_store(o, &outr[tid + 256 * k]);       // stream out
    }
}

extern "C" void kernel_launch(void* const* d_in, const int* in_sizes, int n_in,
                              void* d_out, int out_size, void* d_ws, size_t ws_size,
                              hipStream_t stream) {
    const float* x   = (const float*)d_in[0];   // (8192, 128)
    const float* adj = (const float*)d_in[1];   // (8192, 8192)
    const float* W   = (const float*)d_in[2];   // (256,)
    const float* b   = (const float*)d_in[3];   // scalar (1-elem device array)
    float* out = (float*)d_out;

    float* sL = (float*)d_ws;                   // 8192 floats
    float* sR = sL + NN;                        // 8192 floats

    compute_s_kernel<<<NN / 4, 256, 0, stream>>>(x, W, sL, sR);
    dense_att_row_kernel<<<NN, 256, 0, stream>>>(adj, sL, sR, b, out);
}